// Round 4
// baseline (1852.328 us; speedup 1.0000x reference)
//
#include <hip/hip_runtime.h>
#include <math.h>

#define N_NODES  100000
#define N_HEDGES 50000
#define N_INC    300000
#define N_GRAPHS 1024
#define D_IN     49
#define D        512
#define NPAD     100096   // 782 * 128
#define KPAD_IN  64

typedef __attribute__((ext_vector_type(8))) short short8;
typedef __attribute__((ext_vector_type(4))) float f32x4;

__device__ __forceinline__ short f2bf(float f) {
    union { float f; unsigned u; } v; v.f = f;
    unsigned r = v.u + 0x7fffu + ((v.u >> 16) & 1u);
    return (short)(r >> 16);
}
__device__ __forceinline__ float bf2f(short s) {
    union { unsigned u; float f; } v; v.u = ((unsigned)(unsigned short)s) << 16;
    return v.f;
}

__device__ __forceinline__ void gld16(const void* g, void* l) {
    __builtin_amdgcn_global_load_lds(
        (const __attribute__((address_space(1))) unsigned int*)g,
        (__attribute__((address_space(3))) unsigned int*)l, 16, 0, 0);
}

// ---------------- GEMM: C[M,512] = A[M,K](bf16) @ Bt[512,K](bf16) + bias (+resid_bf16) ----------------
// 128x128 tile, 4 waves (2x2). Staging via global_load_lds(16B) with PRE-SWIZZLED global
// source addresses (LDS dest is linear); ds_read applies the same XOR -> conflict-free.
// 2-phase pipeline: stage(t+1) -> ds_read/MFMA(t) -> one barrier per 32-K step.
__global__ __launch_bounds__(256) void gemm_bf16(
    const short* __restrict__ A, const short* __restrict__ Bt,
    const float* __restrict__ bias, const short* __restrict__ residbf,
    short* __restrict__ Cbf, float* __restrict__ Cf, int K, int nby)
{
    __shared__ short As[2][128][32];
    __shared__ short Bs[2][128][32];
    const int tid  = threadIdx.x;
    const int lane = tid & 63;
    const int wave = tid >> 6;
    const int wr = wave >> 1, wc = wave & 1;

    // bijective XCD-aware swizzle (m204)
    const int nwg = gridDim.x;
    const int q8 = nwg >> 3, r8 = nwg & 7;
    const int xcd = blockIdx.x & 7, loc = blockIdx.x >> 3;
    const int wg = (xcd < r8) ? (xcd * (q8 + 1) + loc) : (r8 * (q8 + 1) + (xcd - r8) * q8 + loc);
    const long row0 = (long)(wg / nby) * 128;
    const int  col0 = (wg % nby) * 128;

    f32x4 acc[4][4];
    #pragma unroll
    for (int m = 0; m < 4; m++)
        #pragma unroll
        for (int n = 0; n < 4; n++)
            acc[m][n] = (f32x4)(0.0f);

    // ---- staging geometry: 8 gl_lds instrs cover 128 rows x 32 cols (8 KB) per operand ----
    // instr q (= wave*2+j) covers LDS rows q*16..q*16+15; lane l -> row q*16 + l/4, chunk l%4.
    // LDS content at (row, c) must be global chunk c ^ sw(row), sw = (row>>1)&3  => pre-swizzle source.
    const int ch   = lane & 3;
    const int rofs = lane >> 2;
    const short* aSrc[2];
    const short* bSrc[2];
    #pragma unroll
    for (int j = 0; j < 2; j++) {
        const int q = wave * 2 + j;
        const int rloc = q * 16 + rofs;
        const int sw = (rloc >> 1) & 3;
        aSrc[j] = A  + (row0 + rloc) * (long)K + (ch ^ sw) * 8;
        bSrc[j] = Bt + ((long)col0 + rloc) * K + (ch ^ sw) * 8;
    }

    const int ks = lane >> 4;
    const int rl = lane & 15;
    const int nk = K >> 5;

    // prologue: stage tile 0 into buf 0
    #pragma unroll
    for (int j = 0; j < 2; j++) {
        const int q = wave * 2 + j;
        gld16(aSrc[j], &As[0][q * 16][0]);
        gld16(bSrc[j], &Bs[0][q * 16][0]);
    }
    __syncthreads();

    int cur = 0;
    for (int t = 0; t < nk; t++) {
        if (t + 1 < nk) {                     // stage next tile into other buffer (in-flight across MFMA)
            const int nxt = cur ^ 1;
            #pragma unroll
            for (int j = 0; j < 2; j++) {
                const int q = wave * 2 + j;
                gld16(aSrc[j] + (t + 1) * 32, &As[nxt][q * 16][0]);
                gld16(bSrc[j] + (t + 1) * 32, &Bs[nxt][q * 16][0]);
            }
        }
        short8 a[4], b[4];
        #pragma unroll
        for (int m = 0; m < 4; m++) {
            const int rr = wr * 64 + m * 16 + rl;
            a[m] = *(const short8*)&As[cur][rr][(ks ^ ((rr >> 1) & 3)) * 8];
        }
        #pragma unroll
        for (int n = 0; n < 4; n++) {
            const int rr = wc * 64 + n * 16 + rl;
            b[n] = *(const short8*)&Bs[cur][rr][(ks ^ ((rr >> 1) & 3)) * 8];
        }
        #pragma unroll
        for (int m = 0; m < 4; m++)
            #pragma unroll
            for (int n = 0; n < 4; n++)
                asm("v_mfma_f32_16x16x32_bf16 %0, %1, %2, %0"
                    : "+v"(acc[m][n]) : "v"(a[m]), "v"(b[n]));
        __syncthreads();                      // drains stage loads; buf[cur^1] ready, buf[cur] reusable
        cur ^= 1;
    }

    const int rl2 = lane & 15;
    const int rb4 = wr * 64 + (lane >> 4) * 4;
    #pragma unroll
    for (int m = 0; m < 4; m++) {
        #pragma unroll
        for (int n = 0; n < 4; n++) {
            const int col = col0 + wc * 64 + n * 16 + rl2;
            const float bi = bias[col];
            #pragma unroll
            for (int rr = 0; rr < 4; rr++) {
                const long row = row0 + rb4 + m * 16 + rr;
                float v = acc[m][n][rr] + bi;
                if (residbf) v += bf2f(residbf[row * D + col]);
                if (Cbf) Cbf[row * D + col] = f2bf(v);
                if (Cf)  Cf[row * D + col]  = v;
            }
        }
    }
}

// ---------------- degree counts ----------------
__global__ void count_inc_kernel(const int* __restrict__ nidx, const int* __restrict__ hidx,
                                 int* cnt_n, int* cnt_h) {
    int i = blockIdx.x * 256 + threadIdx.x;
    if (i < N_INC) {
        atomicAdd(&cnt_h[hidx[i]], 1);
        atomicAdd(&cnt_n[nidx[i]], 1);
    }
}

// single-block exclusive scan
__global__ __launch_bounds__(256) void scan_kernel(const int* __restrict__ cnt, int* __restrict__ off, int n) {
    __shared__ int sums[256];
    int t = threadIdx.x;
    int chunk = (n + 255) / 256;
    int s = t * chunk;
    int e = min(s + chunk, n);
    int loc = 0;
    for (int i = s; i < e; i++) loc += cnt[i];
    sums[t] = loc;
    __syncthreads();
    for (int ofs = 1; ofs < 256; ofs <<= 1) {
        int v = (t >= ofs) ? sums[t - ofs] : 0;
        __syncthreads();
        sums[t] += v;
        __syncthreads();
    }
    int run = (t == 0) ? 0 : sums[t - 1];
    for (int i = s; i < e; i++) { off[i] = run; run += cnt[i]; }
    if (t == 255) off[n] = run;
}

// CSR placement via atomic cursors
__global__ void place_kernel(const int* __restrict__ nidx, const int* __restrict__ hidx,
                             const int* __restrict__ hoff, const int* __restrict__ noff,
                             int* hcur, int* ncur, int* __restrict__ hlist, int* __restrict__ nlist) {
    int e = blockIdx.x * 256 + threadIdx.x;
    if (e < N_INC) {
        int h = hidx[e], n = nidx[e];
        int p = atomicAdd(&hcur[h], 1);
        hlist[hoff[h] + p] = n;
        int q = atomicAdd(&ncur[n], 1);
        nlist[noff[n] + q] = h;
    }
}

// ---------------- weight transpose+convert: W[K,512] f32 -> Wt[512,Kpad] bf16 ----------------
__global__ void wtrans_kernel(const float* __restrict__ W, short* __restrict__ Wt, int K, int Kpad) {
    int n = blockIdx.x;
    for (int k = threadIdx.x; k < Kpad; k += 64)
        Wt[(long)n * Kpad + k] = (k < K) ? f2bf(W[(long)k * D + n]) : (short)0;
}

// node_features [N,49] f32 -> A0 [NPAD,64] bf16 (zero pad)
__global__ void cvt_in_kernel(const float* __restrict__ nf, short* __restrict__ A0) {
    int r = blockIdx.x;
    int c = threadIdx.x;
    short v = 0;
    if (r < N_NODES && c < D_IN) v = f2bf(nf[(long)r * D_IN + c]);
    A0[(long)r * KPAD_IN + c] = v;
}

// hedge gather + msg (bf16 in/out, f32 accum)
__global__ __launch_bounds__(256) void hedge_gather_kernel(
    const short* __restrict__ src, const int* __restrict__ hoff, const int* __restrict__ hlist,
    const int* __restrict__ htype, const float* __restrict__ temb, short* __restrict__ out)
{
    int hrow = blockIdx.x * 4 + (threadIdx.x >> 6);
    if (hrow >= N_HEDGES) return;
    int lane = threadIdx.x & 63;
    int s = hoff[hrow], e = hoff[hrow + 1];
    float acc[8] = {0, 0, 0, 0, 0, 0, 0, 0};
    for (int j = s; j < e; j++) {
        short8 v = *(const short8*)(src + (long)hlist[j] * D + lane * 8);
        #pragma unroll
        for (int k = 0; k < 8; k++) acc[k] += bf2f(v[k]);
    }
    float inv = 1.0f / fmaxf((float)(e - s), 1.0f);
    const float* tp = temb + (long)htype[hrow] * D + lane * 8;
    float4 t0 = *(const float4*)tp;
    float4 t1 = *(const float4*)(tp + 4);
    float tv[8] = {t0.x, t0.y, t0.z, t0.w, t1.x, t1.y, t1.z, t1.w};
    short8 o;
    #pragma unroll
    for (int k = 0; k < 8; k++) o[k] = f2bf(acc[k] * inv + tv[k]);
    *(short8*)(out + (long)hrow * D + lane * 8) = o;
}

// node gather (bf16 in/out)
__global__ __launch_bounds__(256) void node_gather_kernel(
    const short* __restrict__ hmsg, const int* __restrict__ noff, const int* __restrict__ nlist,
    short* __restrict__ Abf)
{
    int r = blockIdx.x * 4 + (threadIdx.x >> 6);
    if (r >= NPAD) return;
    int lane = threadIdx.x & 63;
    short8 o = (short8)0;
    if (r < N_NODES) {
        int s = noff[r], e = noff[r + 1];
        float acc[8] = {0, 0, 0, 0, 0, 0, 0, 0};
        for (int j = s; j < e; j++) {
            short8 v = *(const short8*)(hmsg + (long)nlist[j] * D + lane * 8);
            #pragma unroll
            for (int k = 0; k < 8; k++) acc[k] += bf2f(v[k]);
        }
        float inv = 1.0f / fmaxf((float)(e - s), 1.0f);
        #pragma unroll
        for (int k = 0; k < 8; k++) o[k] = f2bf(acc[k] * inv);
    }
    *(short8*)(Abf + (long)r * D + lane * 8) = o;
}

// LayerNorm + exact GELU, one wave per row; bf16 in, bf16 out (+opt f32)
__global__ __launch_bounds__(256) void ln_gelu_kernel(
    const short* __restrict__ in, short* __restrict__ outbf, float* __restrict__ outf,
    const float* __restrict__ g, const float* __restrict__ b)
{
    const int row = blockIdx.x * 4 + (threadIdx.x >> 6);
    const int lane = threadIdx.x & 63;
    short8 v = *(const short8*)(in + (long)row * D + lane * 8);
    float f[8];
    float s = 0.f, q = 0.f;
    #pragma unroll
    for (int j = 0; j < 8; j++) { f[j] = bf2f(v[j]); s += f[j]; q += f[j] * f[j]; }
    #pragma unroll
    for (int o = 32; o > 0; o >>= 1) { s += __shfl_xor(s, o, 64); q += __shfl_xor(q, o, 64); }
    const float mean = s * (1.0f / D);
    const float var  = q * (1.0f / D) - mean * mean;
    const float rstd = rsqrtf(var + 1e-5f);
    const float4 g0 = *(const float4*)(g + lane * 8);
    const float4 g1 = *(const float4*)(g + lane * 8 + 4);
    const float4 b0 = *(const float4*)(b + lane * 8);
    const float4 b1 = *(const float4*)(b + lane * 8 + 4);
    const float gv[8] = {g0.x, g0.y, g0.z, g0.w, g1.x, g1.y, g1.z, g1.w};
    const float bv[8] = {b0.x, b0.y, b0.z, b0.w, b1.x, b1.y, b1.z, b1.w};
    float yout[8];
    short8 o8;
    #pragma unroll
    for (int j = 0; j < 8; j++) {
        float y = (f[j] - mean) * rstd * gv[j] + bv[j];
        float gl = 0.5f * y * (1.0f + erff(y * 0.70710678118654752f));
        yout[j] = gl;
        o8[j] = f2bf(gl);
    }
    *(short8*)(outbf + (long)row * D + lane * 8) = o8;
    if (outf) {
        float4 o0 = {yout[0], yout[1], yout[2], yout[3]};
        float4 o1 = {yout[4], yout[5], yout[6], yout[7]};
        *(float4*)(outf + (long)row * D + lane * 8) = o0;
        *(float4*)(outf + (long)row * D + lane * 8 + 4) = o1;
    }
}

// graph pooling via sorted batch segments (bf16 in)
__global__ __launch_bounds__(64) void pool_kernel(const short* __restrict__ x, const int* __restrict__ batch,
                                                  short* __restrict__ Gbf) {
    int g = blockIdx.x;
    int lo = 0, hi = N_NODES;
    while (lo < hi) { int mid = (lo + hi) >> 1; if (batch[mid] < g) lo = mid + 1; else hi = mid; }
    int s = lo;
    hi = N_NODES;
    while (lo < hi) { int mid = (lo + hi) >> 1; if (batch[mid] < g + 1) lo = mid + 1; else hi = mid; }
    int e = lo;
    int lane = threadIdx.x;
    float acc[8] = {0, 0, 0, 0, 0, 0, 0, 0};
    for (int r = s; r < e; r++) {
        short8 v = *(const short8*)(x + (long)r * D + lane * 8);
        #pragma unroll
        for (int k = 0; k < 8; k++) acc[k] += bf2f(v[k]);
    }
    float inv = 1.0f / fmaxf((float)(e - s), 1.0f);
    short8 o;
    #pragma unroll
    for (int k = 0; k < 8; k++) o[k] = f2bf(acc[k] * inv);
    *(short8*)(Gbf + (long)g * D + lane * 8) = o;
}

__global__ void batchf_kernel(const int* __restrict__ batch, float* __restrict__ ob) {
    int i = blockIdx.x * 256 + threadIdx.x;
    if (i < N_NODES) ob[i] = (float)batch[i];
}

extern "C" void kernel_launch(void* const* d_in, const int* in_sizes, int n_in,
                              void* d_out, int out_size, void* d_ws, size_t ws_size,
                              hipStream_t stream) {
    (void)in_sizes; (void)n_in; (void)out_size; (void)ws_size;
    const float* nf    = (const float*)d_in[0];
    const int*   nidx  = (const int*)d_in[1];
    const int*   hidx  = (const int*)d_in[2];
    const int*   htype = (const int*)d_in[3];
    const int*   batch = (const int*)d_in[4];
    const float* in_w  = (const float*)d_in[6];
    const float* in_b  = (const float*)d_in[7];
    const float* temb  = (const float*)d_in[8];
    const float* l1w   = (const float*)d_in[9];
    const float* l1b   = (const float*)d_in[10];
    const float* l2w   = (const float*)d_in[11];
    const float* l2b   = (const float*)d_in[12];
    const float* lng   = (const float*)d_in[13];
    const float* lnb   = (const float*)d_in[14];
    const float* outw  = (const float*)d_in[15];
    const float* outb  = (const float*)d_in[16];

    float* out_graph = (float*)d_out;                       // [1024,512]
    float* out_nodes = out_graph + (long)N_GRAPHS * D;      // [100000,512]
    float* out_batch = out_nodes + (long)N_NODES * D;       // [100000]

    char* wsb = (char*)d_ws;
    size_t off = 0;
    auto alloc = [&](size_t bytes) {
        void* p = wsb + off;
        off += (bytes + 255) & ~(size_t)255;
        return p;
    };
    short* x_bf  = (short*)alloc((size_t)NPAD * D * 2);
    short* t1_bf = (short*)alloc((size_t)NPAD * D * 2);
    short* A_bf  = (short*)alloc((size_t)NPAD * D * 2);
    short* h_bf  = (short*)alloc((size_t)N_HEDGES * D * 2);
    short* G_bf  = (short*)alloc((size_t)N_GRAPHS * D * 2);
    short* A0    = (short*)alloc((size_t)NPAD * KPAD_IN * 2);
    short* wt    = (short*)alloc((size_t)D * D * 2);
    int* cnt_h   = (int*)alloc((size_t)N_HEDGES * 4);
    int* cnt_n   = (int*)alloc((size_t)N_NODES * 4);
    int* hoff    = (int*)alloc((size_t)(N_HEDGES + 1) * 4);
    int* noff    = (int*)alloc((size_t)(N_NODES + 1) * 4);
    int* hcur    = (int*)alloc((size_t)N_HEDGES * 4);
    int* ncur    = (int*)alloc((size_t)N_NODES * 4);
    int* hlist   = (int*)alloc((size_t)N_INC * 4);
    int* nlist   = (int*)alloc((size_t)N_INC * 4);

    // ---- build CSR (both directions) ----
    hipMemsetAsync(cnt_h, 0, (size_t)N_HEDGES * 4, stream);
    hipMemsetAsync(cnt_n, 0, (size_t)N_NODES * 4, stream);
    hipMemsetAsync(hcur,  0, (size_t)N_HEDGES * 4, stream);
    hipMemsetAsync(ncur,  0, (size_t)N_NODES * 4, stream);
    count_inc_kernel<<<(N_INC + 255) / 256, 256, 0, stream>>>(nidx, hidx, cnt_n, cnt_h);
    scan_kernel<<<1, 256, 0, stream>>>(cnt_h, hoff, N_HEDGES);
    scan_kernel<<<1, 256, 0, stream>>>(cnt_n, noff, N_NODES);
    place_kernel<<<(N_INC + 255) / 256, 256, 0, stream>>>(nidx, hidx, hoff, noff, hcur, ncur, hlist, nlist);
    batchf_kernel<<<(N_NODES + 255) / 256, 256, 0, stream>>>(batch, out_batch);

    // ---- input projection: x_bf = bf16(nf @ in_w + in_b) ----
    wtrans_kernel<<<D, 64, 0, stream>>>(in_w, wt, D_IN, KPAD_IN);
    cvt_in_kernel<<<NPAD, 64, 0, stream>>>(nf, A0);
    const int NWG = (NPAD / 128) * 4;   // 3128
    gemm_bf16<<<NWG, 256, 0, stream>>>(A0, wt, in_b, nullptr, x_bf, nullptr, KPAD_IN, 4);

    for (int i = 0; i < 3; i++) {
        // t1 = x @ l1_w[i] + l1_b[i]
        wtrans_kernel<<<D, 64, 0, stream>>>(l1w + (size_t)i * D * D, wt, D, D);
        gemm_bf16<<<NWG, 256, 0, stream>>>(x_bf, wt, l1b + i * D, nullptr, t1_bf, nullptr, D, 4);
        // hedge aggregate + msg
        hedge_gather_kernel<<<(N_HEDGES + 3) / 4, 256, 0, stream>>>(t1_bf, hoff, hlist, htype, temb, h_bf);
        // node aggregate
        node_gather_kernel<<<NPAD / 4, 256, 0, stream>>>(h_bf, noff, nlist, A_bf);
        // y = x + node_aggr @ l2_w[i] + l2_b[i]
        wtrans_kernel<<<D, 64, 0, stream>>>(l2w + (size_t)i * D * D, wt, D, D);
        gemm_bf16<<<NWG, 256, 0, stream>>>(A_bf, wt, l2b + i * D, x_bf, t1_bf, nullptr, D, 4);
        // x = gelu(ln(y));  final layer also writes f32 out_nodes
        ln_gelu_kernel<<<N_NODES / 4, 256, 0, stream>>>(t1_bf, x_bf, (i < 2) ? nullptr : out_nodes,
                                                        lng + i * D, lnb + i * D);
    }

    // ---- graph pooling + output projection ----
    pool_kernel<<<N_GRAPHS, 64, 0, stream>>>(x_bf, batch, G_bf);
    wtrans_kernel<<<D, 64, 0, stream>>>(outw, wt, D, D);
    gemm_bf16<<<(N_GRAPHS / 128) * 4, 256, 0, stream>>>(G_bf, wt, outb, nullptr, nullptr, out_graph, D, 4);
}